// Round 11
// baseline (191.078 us; speedup 1.0000x reference)
//
#include <hip/hip_runtime.h>

// LSTM_52922587021316 — Round 14: software-pipeline layer-0 one step ahead.
// Cross-round invariant (R10-R13): dur - VALU-time ≈ 32-38us CONSTANT at
// 40% and 54% occupancy — a TLP-dead serial stall: per-t critical chain
// MFMA g0 -> epi0 -> LDS h1 turnaround -> MFMA g1 wait -> epi1 -> LDS h2
// turnaround. This round: g0(t+1) depends only on Ah1(t) (same operand as
// g1(t)), so issue layer-0 MFMAs for t+1 right after layer-1 MFMAs for t —
// their latency hides under epi1's ~600cy of VALU, removing one MFMA-wait
// per t from the path; Ah2-read latency is covered by epi0(t+1). Copy-free:
// epi0 kills g0c at loop top, prefetch MFMAs overwrite g0c in place.
// t=0 gates = bias + wx*x directly (Ah1=0, no MFMA). Bit-identical math.
// VGPR 48 -> ~80-96: LDS still binds (4 blocks/CU) and <=128 keeps the
// 4-waves/SIMD quantum -> occupancy unchanged. (256,2) cap 256 -> no
// forced spill. Tripwires: VGPR>128, WRITE_SIZE>2MB.

#define HID 32
#define TSTEPS 7
#define LSTRIDE 36   // halves per LDS h-row: 32 + 4 pad (72 B)
#define NWAVES 4     // waves per block

typedef _Float16 half8 __attribute__((ext_vector_type(8)));
typedef float floatx4 __attribute__((ext_vector_type(4)));
typedef float floatx2 __attribute__((ext_vector_type(2)));

#define LOG2E 1.44269504088896f

__device__ __forceinline__ float fast_rcp(float x) { return __builtin_amdgcn_rcpf(x); }

__device__ __forceinline__ float exp2_fast(float x) {
#if __has_builtin(__builtin_amdgcn_exp2f)
    return __builtin_amdgcn_exp2f(x);
#else
    return __expf(x * 0.69314718055994531f);
#endif
}

__device__ __forceinline__ floatx2 mk2(float a, float b) {
    floatx2 v; v[0] = a; v[1] = b; return v;
}
__device__ __forceinline__ floatx2 exp2_v2(floatx2 a) {
    return mk2(exp2_fast(a[0]), exp2_fast(a[1]));
}

// v2.5 cell update on an h-pair (proven absmax 9.77e-4 in R11/R13):
// Rb/Rm/Rh pair-batched, c-recurrence sum structure untouched.
// Full-rate arithmetic on <2 x float> -> v_pk_* on gfx950.
__device__ __forceinline__ floatx2 cell_pair(floatx2 gi, floatx2 gf,
                                             floatx2 gg, floatx2 go,
                                             floatx2& cst) {
    const floatx2 one = mk2(1.0f, 1.0f);
    const floatx2 Ea = exp2_v2(gi);
    const floatx2 Db = exp2_v2(gf) + one;
    const floatx2 Ed = exp2_v2(gg);
    const floatx2 Ee = exp2_v2(go);
    const floatx2 M  = (Ea + one) * (Ed + one);
    const float Rb = fast_rcp(Db[0] * Db[1]);
    const float Rm = fast_rcp(M[0] * M[1]);
    const floatx2 ff  = mk2(Rb, Rb) * mk2(Db[1], Db[0]);
    const floatx2 rig = mk2(Rm, Rm) * mk2(M[1], M[0]);
    const floatx2 ig  = __builtin_elementwise_fma(Ed, rig, -rig);
    const floatx2 c   = __builtin_elementwise_fma(ff, cst, ig);
    cst = c;
    const floatx2 Ec  = exp2_v2(c * mk2(2.0f * LOG2E, 2.0f * LOG2E));
    const floatx2 Dh  = (Ee + one) * (Ec + one);
    const float Rh = fast_rcp(Dh[0] * Dh[1]);
    const floatx2 th = mk2(Rh, Rh) * mk2(Dh[1], Dh[0]);
    return __builtin_elementwise_fma(Ec, th, -th);
}

__global__ __launch_bounds__(256, 2) void lstm2_mfma(
    const float* __restrict__ xin,   // [B, 7]
    const float* __restrict__ Wih0,  // [128, 1]
    const float* __restrict__ Whh0,  // [128, 32]
    const float* __restrict__ bih0,  // [128]
    const float* __restrict__ bhh0,  // [128]
    const float* __restrict__ Wih1,  // [128, 32]
    const float* __restrict__ Whh1,  // [128, 32]
    const float* __restrict__ bih1,  // [128]
    const float* __restrict__ bhh1,  // [128]
    const float* __restrict__ fcw,   // [32]
    const float* __restrict__ fcb,   // [1]
    const float* __restrict__ fc1w,  // [7]
    const float* __restrict__ fc1b,  // [1]
    float* __restrict__ out,         // [B]
    int B)
{
    const int lane = threadIdx.x & 63;
    const int wave = threadIdx.x >> 6;
    const int col  = lane & 15;          // C col / A row m
    const int rg   = lane >> 4;          // C rows rg*4..+3 / A k-chunk rg*8..+7
    const int seq_base = (blockIdx.x * NWAVES + wave) * 16;

    // Weight fragments, block-shared, per-lane order:
    // matrix m in {0:Whh0, 1:Wih1, 2:Whh1}, tile nt (0..7), lane, 8 halves.
    // byte offset = m*8192 + nt*1024 + lane*16  -> ds_read_b128, conflict-free.
    __shared__ __align__(16) _Float16 ldsw[3 * 8 * 64 * 8];   // 24 KiB
    __shared__ __align__(16) floatx2  ldsbw0[128];            // {b0s, wx} by n, 1 KiB
    __shared__ float                  ldsb1[128];             // b1s by n, 0.5 KiB
    __shared__ __align__(16) _Float16 ldsh[NWAVES][16 * LSTRIDE];  // ONE h-buffer/wave
    __shared__ __align__(16) float    ldsx[NWAVES][TSTEPS * 16];

    _Float16* hl = &ldsh[wave][0];   // shared by h1 and h2 (same-wave DS in-order)
    float* xl = &ldsx[wave][0];

    // ---- stage x: 112 contiguous floats per wave -> transposed [t][seq] ---
#pragma unroll
    for (int e = lane; e < TSTEPS * 16; e += 64) {
        const int s = e / TSTEPS;
        const int tt = e - s * TSTEPS;
        xl[tt * 16 + s] = xin[seq_base * TSTEPS + e];
    }

    // ---- stage prescaled weights/biases into LDS (once per block) --------
    if (wave < 3) {
        const float* Wsrc = (wave == 0) ? Whh0 : (wave == 1) ? Wih1 : Whh1;
#pragma unroll
        for (int nt = 0; nt < 8; ++nt) {
            const int n = nt * 16 + col;
            const float sc = ((n >> 5) == 2) ? (2.0f * LOG2E) : (-LOG2E);
            const float* s = Wsrc + n * HID + rg * 8;
            half8 f;
#pragma unroll
            for (int j = 0; j < 8; ++j) f[j] = (_Float16)(sc * s[j]);
            *(half8*)&ldsw[((wave * 8 + nt) * 64 + lane) * 8] = f;
        }
    } else {
#pragma unroll
        for (int i = 0; i < 2; ++i) {
            const int n = i * 64 + lane;
            const float sc = ((n >> 5) == 2) ? (2.0f * LOG2E) : (-LOG2E);
            floatx2 bw;
            bw[0] = sc * (bih0[n] + bhh0[n]);   // prescaled layer-0 bias
            bw[1] = sc * Wih0[n];               // prescaled rank-1 x weight
            ldsbw0[n] = bw;
            ldsb1[n]  = sc * (bih1[n] + bhh1[n]);
        }
    }
    __syncthreads();

    const float fcw_l0 = fcw[col];
    const float fcw_l1 = fcw[16 + col];

    half8 Ah2 = {};      // h2 in A-layout
    floatx2 c1v[2][2] = {}, c2v[2][2] = {};   // cell states as pk pairs
    floatx2 faccv[2] = {};                     // fc partials as pk pairs

    // ---- t=0 layer-0 gates: Ah1 == 0, so gates = bias + wx*x (no MFMA) ---
    floatx4 g0c[8];
    {
        const floatx4 xr0 = *(const floatx4*)&xl[rg * 4];
        const char* bB0p = (const char*)ldsbw0 + col * 8;
#pragma unroll
        for (int nt = 0; nt < 8; ++nt) {
            const floatx2 bw = *(const floatx2*)(bB0p + nt * 128);
#pragma unroll
            for (int r = 0; r < 4; ++r) g0c[nt][r] = fmaf(bw[1], xr0[r], bw[0]);
        }
    }

    for (int t = 0; t < TSTEPS; ++t) {
        // Opaque zero offset: makes the LDS weight addresses loop-variant so
        // LICM cannot hoist the fragment loads back into 96 registers.
        unsigned woff = 0;
        asm volatile("" : "+v"(woff));
        const char* wB  = (const char*)ldsw   + lane * 16 + woff;
        const char* bB0 = (const char*)ldsbw0 + col * 8  + woff;
        const char* bB1 = (const char*)ldsb1  + col * 4  + woff;

        // epilogue 0: consume g0c (gates for this t), write h1_new
#pragma unroll
        for (int q = 0; q < 2; ++q) {
#pragma unroll
            for (int rp = 0; rp < 2; ++rp) {
                const floatx2 h = cell_pair(
                    mk2(g0c[0 + q][rp * 2], g0c[0 + q][rp * 2 + 1]),
                    mk2(g0c[2 + q][rp * 2], g0c[2 + q][rp * 2 + 1]),
                    mk2(g0c[4 + q][rp * 2], g0c[4 + q][rp * 2 + 1]),
                    mk2(g0c[6 + q][rp * 2], g0c[6 + q][rp * 2 + 1]),
                    c1v[q][rp]);
                hl[(rg * 4 + rp * 2 + 0) * LSTRIDE + q * 16 + col] = (_Float16)h[0];
                hl[(rg * 4 + rp * 2 + 1) * LSTRIDE + q * 16 + col] = (_Float16)h[1];
            }
        }
        const half8 Ah1 = *(const half8*)&hl[col * LSTRIDE + rg * 8];

        // -------- layer 1 MFMAs for t: bias + h1_new@Wih1^T + h2@Whh1^T ---
        floatx4 g1[8];
#pragma unroll
        for (int nt = 0; nt < 8; ++nt) {
            const float b1  = *(const float*)(bB1 + nt * 64);
            const half8 f1a = *(const half8*)(wB + 8192  + nt * 1024);
            const half8 f1b = *(const half8*)(wB + 16384 + nt * 1024);
            floatx4 c = {b1, b1, b1, b1};
            c = __builtin_amdgcn_mfma_f32_16x16x32_f16(Ah1, f1a, c, 0, 0, 0);
            g1[nt] = __builtin_amdgcn_mfma_f32_16x16x32_f16(Ah2, f1b, c, 0, 0, 0);
        }

        // -------- PREFETCH layer-0 MFMAs for t+1 (depend only on Ah1) -----
        // Overwrites g0c (dead after epilogue 0). Latency hides under epi1.
        if (t + 1 < TSTEPS) {
            const floatx4 xr = *(const floatx4*)&xl[(t + 1) * 16 + rg * 4];
#pragma unroll
            for (int nt = 0; nt < 8; ++nt) {
                const floatx2 bw = *(const floatx2*)(bB0 + nt * 128);
                const half8 bf   = *(const half8*)(wB + nt * 1024);
                floatx4 c;
#pragma unroll
                for (int r = 0; r < 4; ++r) c[r] = fmaf(bw[1], xr[r], bw[0]);
                g0c[nt] = __builtin_amdgcn_mfma_f32_16x16x32_f16(Ah1, bf, c, 0, 0, 0);
            }
        }

        // epilogue 1: consume g1, fc partial, write h2_new over h1
        // (Ah1 already consumed; same-wave DS in-order makes this safe)
        const float f1t = fc1w[t];
        const float w0 = f1t * fcw_l0;
        const float w1 = f1t * fcw_l1;
#pragma unroll
        for (int q = 0; q < 2; ++q) {
            const float wq = q ? w1 : w0;
            const floatx2 wqv = mk2(wq, wq);
#pragma unroll
            for (int rp = 0; rp < 2; ++rp) {
                const floatx2 h = cell_pair(
                    mk2(g1[0 + q][rp * 2], g1[0 + q][rp * 2 + 1]),
                    mk2(g1[2 + q][rp * 2], g1[2 + q][rp * 2 + 1]),
                    mk2(g1[4 + q][rp * 2], g1[4 + q][rp * 2 + 1]),
                    mk2(g1[6 + q][rp * 2], g1[6 + q][rp * 2 + 1]),
                    c2v[q][rp]);
                faccv[rp] = __builtin_elementwise_fma(wqv, h, faccv[rp]);
                hl[(rg * 4 + rp * 2 + 0) * LSTRIDE + q * 16 + col] = (_Float16)h[0];
                hl[(rg * 4 + rp * 2 + 1) * LSTRIDE + q * 16 + col] = (_Float16)h[1];
            }
        }
        Ah2 = *(const half8*)&hl[col * LSTRIDE + rg * 8];
    }

    // ---- reduce fc partials across the 16 cols, add constant tail --------
    float facc[4];
#pragma unroll
    for (int r = 0; r < 4; ++r) facc[r] = faccv[r >> 1][r & 1];
#pragma unroll
    for (int r = 0; r < 4; ++r) {
        float v = facc[r];
        v += __shfl_xor(v, 1);
        v += __shfl_xor(v, 2);
        v += __shfl_xor(v, 4);
        v += __shfl_xor(v, 8);
        facc[r] = v;
    }
    float sum_f1 = 0.f;
#pragma unroll
    for (int t = 0; t < TSTEPS; ++t) sum_f1 += fc1w[t];
    const float tail = fcb[0] * sum_f1 + fc1b[0];

    if (col == 0) {
#pragma unroll
        for (int r = 0; r < 4; ++r)
            out[seq_base + rg * 4 + r] = facc[r] + tail;
    }
}

extern "C" void kernel_launch(void* const* d_in, const int* in_sizes, int n_in,
                              void* d_out, int out_size, void* d_ws, size_t ws_size,
                              hipStream_t stream) {
    const float* xin  = (const float*)d_in[0];
    const float* Wih0 = (const float*)d_in[1];
    const float* Whh0 = (const float*)d_in[2];
    const float* bih0 = (const float*)d_in[3];
    const float* bhh0 = (const float*)d_in[4];
    const float* Wih1 = (const float*)d_in[5];
    const float* Whh1 = (const float*)d_in[6];
    const float* bih1 = (const float*)d_in[7];
    const float* bhh1 = (const float*)d_in[8];
    const float* fcw  = (const float*)d_in[9];
    const float* fcb  = (const float*)d_in[10];
    const float* fc1w = (const float*)d_in[11];
    const float* fc1b = (const float*)d_in[12];
    float* out = (float*)d_out;

    const int B = in_sizes[0] / TSTEPS;       // [B, T, F=1]
    const int grid = B / (NWAVES * 16);       // 1 block = 4 waves = 64 sequences
    lstm2_mfma<<<grid, NWAVES * 64, 0, stream>>>(
        xin, Wih0, Whh0, bih0, bhh0, Wih1, Whh1, bih1, bhh1,
        fcw, fcb, fc1w, fc1b, out, B);
}

// Round 12
// 186.735 us; speedup vs baseline: 1.0233x; 1.0233x over previous
//
#include <hip/hip_runtime.h>

// LSTM_52922587021316 — Round 15: R13 verbatim in an 8-wave (512,2) shell.
// R14 lesson: pipelining's gain exactly paid its VGPR-quantum crossing
// (48->68 regs, occ 40->31%) — reverted. Shell re-audit: R6/R8's "512-thread
// spill" was really the launch_bounds ',6' (budget 85) forcing allocator
// pathology (VGPR 40 + scratch). Block size was innocent. With (512,2) the
// budget is 256 — same slack as every clean 256-thread shell.
// Why 8-wave blocks now: R13 is 48 VGPR (cap 32 waves/CU) but 4-wave blocks
// amortize the 26KiB weight-LDS badly: 38400x4 -> LDS caps 16 waves/CU (50%).
// 8-wave blocks, same per-lane code: LDS 38912 -> 4 blocks/CU x 8 waves =
// 32 waves/CU cap (155648 <= 163840, 8KB slack — not R12's refused exact
// fit). Waves need ~28% issue duty; 5-6/SIMD oversubscribes the port ->
// VALUBusy toward the ~97us VALU-work floor. Predict dur 103-118us.
// Tripwires: WRITE>2MB (allocator pathology) -> revert shell; VGPR>64.

#define HID 32
#define TSTEPS 7
#define LSTRIDE 36   // halves per LDS h-row: 32 + 4 pad (72 B)
#define NWAVES 8     // waves per block

typedef _Float16 half8 __attribute__((ext_vector_type(8)));
typedef float floatx4 __attribute__((ext_vector_type(4)));
typedef float floatx2 __attribute__((ext_vector_type(2)));

#define LOG2E 1.44269504088896f

__device__ __forceinline__ float fast_rcp(float x) { return __builtin_amdgcn_rcpf(x); }

__device__ __forceinline__ float exp2_fast(float x) {
#if __has_builtin(__builtin_amdgcn_exp2f)
    return __builtin_amdgcn_exp2f(x);
#else
    return __expf(x * 0.69314718055994531f);
#endif
}

__device__ __forceinline__ floatx2 mk2(float a, float b) {
    floatx2 v; v[0] = a; v[1] = b; return v;
}
__device__ __forceinline__ floatx2 exp2_v2(floatx2 a) {
    return mk2(exp2_fast(a[0]), exp2_fast(a[1]));
}

// v2.5 cell update on an h-pair (proven absmax 9.77e-4 in R11/R13):
// Rb/Rm/Rh pair-batched, c-recurrence sum structure untouched.
// Full-rate arithmetic on <2 x float> -> v_pk_* on gfx950.
__device__ __forceinline__ floatx2 cell_pair(floatx2 gi, floatx2 gf,
                                             floatx2 gg, floatx2 go,
                                             floatx2& cst) {
    const floatx2 one = mk2(1.0f, 1.0f);
    const floatx2 Ea = exp2_v2(gi);
    const floatx2 Db = exp2_v2(gf) + one;
    const floatx2 Ed = exp2_v2(gg);
    const floatx2 Ee = exp2_v2(go);
    const floatx2 M  = (Ea + one) * (Ed + one);
    const float Rb = fast_rcp(Db[0] * Db[1]);
    const float Rm = fast_rcp(M[0] * M[1]);
    const floatx2 ff  = mk2(Rb, Rb) * mk2(Db[1], Db[0]);
    const floatx2 rig = mk2(Rm, Rm) * mk2(M[1], M[0]);
    const floatx2 ig  = __builtin_elementwise_fma(Ed, rig, -rig);
    const floatx2 c   = __builtin_elementwise_fma(ff, cst, ig);
    cst = c;
    const floatx2 Ec  = exp2_v2(c * mk2(2.0f * LOG2E, 2.0f * LOG2E));
    const floatx2 Dh  = (Ee + one) * (Ec + one);
    const float Rh = fast_rcp(Dh[0] * Dh[1]);
    const floatx2 th = mk2(Rh, Rh) * mk2(Dh[1], Dh[0]);
    return __builtin_elementwise_fma(Ec, th, -th);
}

__global__ __launch_bounds__(512, 2) void lstm2_mfma(
    const float* __restrict__ xin,   // [B, 7]
    const float* __restrict__ Wih0,  // [128, 1]
    const float* __restrict__ Whh0,  // [128, 32]
    const float* __restrict__ bih0,  // [128]
    const float* __restrict__ bhh0,  // [128]
    const float* __restrict__ Wih1,  // [128, 32]
    const float* __restrict__ Whh1,  // [128, 32]
    const float* __restrict__ bih1,  // [128]
    const float* __restrict__ bhh1,  // [128]
    const float* __restrict__ fcw,   // [32]
    const float* __restrict__ fcb,   // [1]
    const float* __restrict__ fc1w,  // [7]
    const float* __restrict__ fc1b,  // [1]
    float* __restrict__ out,         // [B]
    int B)
{
    const int lane = threadIdx.x & 63;
    const int wave = threadIdx.x >> 6;
    const int col  = lane & 15;          // C col / A row m
    const int rg   = lane >> 4;          // C rows rg*4..+3 / A k-chunk rg*8..+7
    const int seq_base = (blockIdx.x * NWAVES + wave) * 16;

    // Weight fragments, block-shared, per-lane order:
    // matrix m in {0:Whh0, 1:Wih1, 2:Whh1}, tile nt (0..7), lane, 8 halves.
    // byte offset = m*8192 + nt*1024 + lane*16  -> ds_read_b128, conflict-free.
    __shared__ __align__(16) _Float16 ldsw[3 * 8 * 64 * 8];   // 24 KiB
    __shared__ __align__(16) floatx2  ldsbw0[128];            // {b0s, wx} by n, 1 KiB
    __shared__ float                  ldsb1[128];             // b1s by n, 0.5 KiB
    __shared__ __align__(16) _Float16 ldsh[NWAVES][16 * LSTRIDE];  // ONE h-buffer/wave
    __shared__ __align__(16) float    ldsx[NWAVES][TSTEPS * 16];

    _Float16* hl = &ldsh[wave][0];   // shared by h1 and h2 (same-wave DS in-order)
    float* xl = &ldsx[wave][0];

    // ---- stage x: 112 contiguous floats per wave -> transposed [t][seq] ---
#pragma unroll
    for (int e = lane; e < TSTEPS * 16; e += 64) {
        const int s = e / TSTEPS;
        const int tt = e - s * TSTEPS;
        xl[tt * 16 + s] = xin[seq_base * TSTEPS + e];
    }

    // ---- stage prescaled weights/biases into LDS (once per block) --------
    if (wave < 3) {
        const float* Wsrc = (wave == 0) ? Whh0 : (wave == 1) ? Wih1 : Whh1;
#pragma unroll
        for (int nt = 0; nt < 8; ++nt) {
            const int n = nt * 16 + col;
            const float sc = ((n >> 5) == 2) ? (2.0f * LOG2E) : (-LOG2E);
            const float* s = Wsrc + n * HID + rg * 8;
            half8 f;
#pragma unroll
            for (int j = 0; j < 8; ++j) f[j] = (_Float16)(sc * s[j]);
            *(half8*)&ldsw[((wave * 8 + nt) * 64 + lane) * 8] = f;
        }
    } else if (wave == 3) {
#pragma unroll
        for (int i = 0; i < 2; ++i) {
            const int n = i * 64 + lane;
            const float sc = ((n >> 5) == 2) ? (2.0f * LOG2E) : (-LOG2E);
            floatx2 bw;
            bw[0] = sc * (bih0[n] + bhh0[n]);   // prescaled layer-0 bias
            bw[1] = sc * Wih0[n];               // prescaled rank-1 x weight
            ldsbw0[n] = bw;
            ldsb1[n]  = sc * (bih1[n] + bhh1[n]);
        }
    }
    __syncthreads();

    const float fcw_l0 = fcw[col];
    const float fcw_l1 = fcw[16 + col];

    half8 Ah1 = {};      // h1 in A-layout (zero at t=0)
    half8 Ah2 = {};      // h2 in A-layout
    floatx2 c1v[2][2] = {}, c2v[2][2] = {};   // cell states as pk pairs
    floatx2 faccv[2] = {};                     // fc partials as pk pairs

    for (int t = 0; t < TSTEPS; ++t) {
        // Opaque zero offset: makes the LDS weight addresses loop-variant so
        // LICM cannot hoist the 24 fragment loads back into 96 registers.
        unsigned woff = 0;
        asm volatile("" : "+v"(woff));
        const char* wB  = (const char*)ldsw   + lane * 16 + woff;
        const char* bB0 = (const char*)ldsbw0 + col * 8  + woff;
        const char* bB1 = (const char*)ldsb1  + col * 4  + woff;

        // x for my 4 C-rows (m = rg*4 + r): one b128, conflict-free broadcast
        const floatx4 xr = *(const floatx4*)&xl[t * 16 + rg * 4];

        // -------- layer 0: gates = (bias + x*Wih0) + h1_prev @ Whh0^T -----
        floatx4 g0[8];
#pragma unroll
        for (int nt = 0; nt < 8; ++nt) {
            const floatx2 bw = *(const floatx2*)(bB0 + nt * 128);
            const half8 bf   = *(const half8*)(wB + nt * 1024);
            const floatx2 wv = mk2(bw[1], bw[1]);
            const floatx2 bv = mk2(bw[0], bw[0]);
            const floatx2 clo = __builtin_elementwise_fma(wv, mk2(xr[0], xr[1]), bv);
            const floatx2 chi = __builtin_elementwise_fma(wv, mk2(xr[2], xr[3]), bv);
            floatx4 c;
            c[0] = clo[0]; c[1] = clo[1]; c[2] = chi[0]; c[3] = chi[1];
            g0[nt] = __builtin_amdgcn_mfma_f32_16x16x32_f16(Ah1, bf, c, 0, 0, 0);
        }

        // epilogue 0: packed v2.5 cell update, write h1_new
#pragma unroll
        for (int q = 0; q < 2; ++q) {
#pragma unroll
            for (int rp = 0; rp < 2; ++rp) {
                const floatx2 h = cell_pair(
                    mk2(g0[0 + q][rp * 2], g0[0 + q][rp * 2 + 1]),
                    mk2(g0[2 + q][rp * 2], g0[2 + q][rp * 2 + 1]),
                    mk2(g0[4 + q][rp * 2], g0[4 + q][rp * 2 + 1]),
                    mk2(g0[6 + q][rp * 2], g0[6 + q][rp * 2 + 1]),
                    c1v[q][rp]);
                hl[(rg * 4 + rp * 2 + 0) * LSTRIDE + q * 16 + col] = (_Float16)h[0];
                hl[(rg * 4 + rp * 2 + 1) * LSTRIDE + q * 16 + col] = (_Float16)h[1];
            }
        }
        Ah1 = *(const half8*)&hl[col * LSTRIDE + rg * 8];

        // -------- layer 1: gates = bias + h1_new @ Wih1^T + h2_prev @ Whh1^T
        floatx4 g1[8];
#pragma unroll
        for (int nt = 0; nt < 8; ++nt) {
            const float b1  = *(const float*)(bB1 + nt * 64);
            const half8 f1a = *(const half8*)(wB + 8192  + nt * 1024);
            const half8 f1b = *(const half8*)(wB + 16384 + nt * 1024);
            floatx4 c = {b1, b1, b1, b1};
            c = __builtin_amdgcn_mfma_f32_16x16x32_f16(Ah1, f1a, c, 0, 0, 0);
            g1[nt] = __builtin_amdgcn_mfma_f32_16x16x32_f16(Ah2, f1b, c, 0, 0, 0);
        }

        // epilogue 1: packed v2.5 cell update, fc partial, write h2 over h1
        // (Ah1 already consumed; same-wave DS in-order makes this safe)
        const float f1t = fc1w[t];
        const float w0 = f1t * fcw_l0;
        const float w1 = f1t * fcw_l1;
#pragma unroll
        for (int q = 0; q < 2; ++q) {
            const float wq = q ? w1 : w0;
            const floatx2 wqv = mk2(wq, wq);
#pragma unroll
            for (int rp = 0; rp < 2; ++rp) {
                const floatx2 h = cell_pair(
                    mk2(g1[0 + q][rp * 2], g1[0 + q][rp * 2 + 1]),
                    mk2(g1[2 + q][rp * 2], g1[2 + q][rp * 2 + 1]),
                    mk2(g1[4 + q][rp * 2], g1[4 + q][rp * 2 + 1]),
                    mk2(g1[6 + q][rp * 2], g1[6 + q][rp * 2 + 1]),
                    c2v[q][rp]);
                faccv[rp] = __builtin_elementwise_fma(wqv, h, faccv[rp]);
                hl[(rg * 4 + rp * 2 + 0) * LSTRIDE + q * 16 + col] = (_Float16)h[0];
                hl[(rg * 4 + rp * 2 + 1) * LSTRIDE + q * 16 + col] = (_Float16)h[1];
            }
        }
        Ah2 = *(const half8*)&hl[col * LSTRIDE + rg * 8];
    }

    // ---- reduce fc partials across the 16 cols, add constant tail --------
    float facc[4];
#pragma unroll
    for (int r = 0; r < 4; ++r) facc[r] = faccv[r >> 1][r & 1];
#pragma unroll
    for (int r = 0; r < 4; ++r) {
        float v = facc[r];
        v += __shfl_xor(v, 1);
        v += __shfl_xor(v, 2);
        v += __shfl_xor(v, 4);
        v += __shfl_xor(v, 8);
        facc[r] = v;
    }
    float sum_f1 = 0.f;
#pragma unroll
    for (int t = 0; t < TSTEPS; ++t) sum_f1 += fc1w[t];
    const float tail = fcb[0] * sum_f1 + fc1b[0];

    if (col == 0) {
#pragma unroll
        for (int r = 0; r < 4; ++r)
            out[seq_base + rg * 4 + r] = facc[r] + tail;
    }
}

extern "C" void kernel_launch(void* const* d_in, const int* in_sizes, int n_in,
                              void* d_out, int out_size, void* d_ws, size_t ws_size,
                              hipStream_t stream) {
    const float* xin  = (const float*)d_in[0];
    const float* Wih0 = (const float*)d_in[1];
    const float* Whh0 = (const float*)d_in[2];
    const float* bih0 = (const float*)d_in[3];
    const float* bhh0 = (const float*)d_in[4];
    const float* Wih1 = (const float*)d_in[5];
    const float* Whh1 = (const float*)d_in[6];
    const float* bih1 = (const float*)d_in[7];
    const float* bhh1 = (const float*)d_in[8];
    const float* fcw  = (const float*)d_in[9];
    const float* fcb  = (const float*)d_in[10];
    const float* fc1w = (const float*)d_in[11];
    const float* fc1b = (const float*)d_in[12];
    float* out = (float*)d_out;

    const int B = in_sizes[0] / TSTEPS;       // [B, T, F=1]
    const int grid = B / (NWAVES * 16);       // 1 block = 8 waves = 128 sequences
    lstm2_mfma<<<grid, NWAVES * 64, 0, stream>>>(
        xin, Wih0, Whh0, bih0, bhh0, Wih1, Whh1, bih1, bhh1,
        fcw, fcb, fc1w, fc1b, out, B);
}